// Round 12
// baseline (121.729 us; speedup 1.0000x reference)
//
#include <hip/hip_runtime.h>
#include <hip/hip_bf16.h>
#include <stdint.h>
#include <string.h>

typedef __attribute__((ext_vector_type(8))) short short8;   // 8 bf16 (4 VGPRs) MFMA operand
typedef __attribute__((ext_vector_type(4))) float floatx4;  // MFMA accumulator

#define NPTS 256   // points per group
#define DIM  256   // feature dim
#define TILE 128   // output tile per block
#define BK   32    // K-slice width (one 16x16x32 MFMA K)
#define NIT  (DIM / BK)          // 8 K-slices
#define SLICE (TILE * BK)        // 4096 bf16 elems = 8 KB per slice

// HW packed fp32->bf16 RNE convert (v_cvt_pk_bf16_f32 on gfx950).
static __device__ __forceinline__ uint32_t cvt2(float a, float b) {
    __hip_bfloat162 h = __float22bfloat162_rn(float2{a, b});
    uint32_t d;
    memcpy(&d, &h, 4);
    return d;
}
// squared-sum of 8 fp32 (row-norm partial on original fp32; ~2^-7 relative
// delta vs rounded — far below accepted bf16 Gram error; diagonal forced 0).
static __device__ __forceinline__ float sq8(const float4 u, const float4 v) {
    return u.x * u.x + u.y * u.y + u.z * u.z + u.w * u.w +
           v.x * v.x + v.y * v.y + v.z * v.z + v.w * v.w;
}

// ---------------------------------------------------------------------------
// mmd_mono: whole-panel LDS residency, barrier-free K-loop.
// grid = 10*G blocks, XCD-swizzled (verified). t 0..3 = XY (w=+1), 4..6 = XX
// upper-tri (w=-0.5/-1/-0.5), 7..9 = YY upper-tri.
//
// DIM=256 is small enough that BOTH full bf16 panels fit in LDS at once:
// As[8][128*32] + Bs[8][128*32] = 128 KB (the guide's verified 8-phase
// example uses the same 128 KB). Stage everything once (load-ahead-1),
// ONE barrier, then 8 K-iterations of pure ds_read+MFMA with NO barriers —
// the compiler software-pipelines freely with fine-grained lgkmcnt (its
// verified strength), removing the 9-barrier convergence stalls that held
// the old pipeline at ~2400cyc/iter vs ~200cyc of issue work.
//
// Slice-major layout keeps the HW-verified conflict-free swizzle per slice:
// within As[s]: addr = row*32 + (chunk ^ ((row>>1)&3))*8  (same formula,
// SQ_LDS_BANK_CONFLICT measured 0 in rounds 4-11).
//
// Norm share: after the K-loop all slices are dead -> reuse As[0] as the
// float share buffer (rnorm | cnorm | wave partials), keeping LDS at exactly
// 128 KB. 4 barriers total (vs 9).
//
// 1 block/CU (LDS-bound); __launch_bounds__(512,2) gives the register
// allocator headroom (<=128 VGPR costs nothing at 1 block/CU residency).
// ---------------------------------------------------------------------------
__global__ __launch_bounds__(512, 2)
void mmd_mono(const float* __restrict__ X, const float* __restrict__ Y,
              float* __restrict__ out, float scale, int G) {
    // ---- block -> (group, tile) decode with XCD swizzle ----
    int g, t;
    const int f = blockIdx.x;
    if ((G & 7) == 0) { const int xcd = f & 7, j = f >> 3; g = (j / 10) * 8 + xcd; t = j % 10; }
    else              { g = f / 10; t = f % 10; }

    int ptype, ti, tj; float w;
    if (t < 4)      { ptype = 0; ti = t >> 1; tj = t & 1; w = 1.0f; }
    else if (t < 7) { int u = t - 4; ptype = 1; ti = (u == 2); tj = (u >= 1); w = (u == 1) ? -1.0f : -0.5f; }
    else            { int u = t - 7; ptype = 2; ti = (u == 2); tj = (u >= 1); w = (u == 1) ? -1.0f : -0.5f; }

    const float *Pf, *Qf;
    if (ptype == 0)      { Pf = X; Qf = Y; }
    else if (ptype == 1) { Pf = X; Qf = X; }
    else                 { Pf = Y; Qf = Y; }
    const bool symdiag = (ptype != 0) && (ti == tj);

    const size_t prow0 = (size_t)g * NPTS + (size_t)ti * TILE;
    const size_t qrow0 = (size_t)g * NPTS + (size_t)tj * TILE;

    __shared__ __align__(16) uint16_t As[NIT][SLICE];  // 64 KB
    __shared__ __align__(16) uint16_t Bs[NIT][SLICE];  // 64 KB
    float* nsh = (float*)&As[0][0];    // reused AFTER K-loop: [0..128)=rnorm,
                                       // [128..256)=cnorm, [256..264)=wpart

    const int tid  = threadIdx.x;          // 0..511
    const int lane = tid & 63;
    const int wv   = tid >> 6;             // 0..7
    const int quad = lane >> 4;
    const int l15  = lane & 15;
    const int rowbase = (wv & 3) * 32;     // wave's 32-row stripe
    const int colbase = (wv >> 2) * 64;    // wave's 64-col stripe
    // fragment read: row = base16 + l15 -> (row>>1)&3 == (l15>>1)&3
    const int rsw = (quad ^ ((l15 >> 1) & 3)) * 8;   // swizzled elem offset

    // ---- producer geometry: thread covers row tid>>2, 16B chunk tid&3 ----
    const int prow = tid >> 2;
    const int pchk = tid & 3;
    const float* gA = Pf + (prow0 + prow) * DIM + pchk * 8;
    const int woff = prow * BK + ((pchk ^ ((prow >> 1) & 3)) * 8);  // swizzled

    float sqp = 0.0f, sqq = 0.0f;          // this thread's partial row norms

    // ================= staging: all 8 slices, load-ahead-1 =================
    if (symdiag) {
        float4 a0 = *(const float4*)(gA);
        float4 a1 = *(const float4*)(gA + 4);
        #pragma unroll
        for (int s = 0; s < NIT; ++s) {
            float4 na0, na1;
            if (s < NIT - 1) {
                na0 = *(const float4*)(gA + (s + 1) * BK);
                na1 = *(const float4*)(gA + (s + 1) * BK + 4);
            }
            sqp += sq8(a0, a1);
            uint4 pa;
            pa.x = cvt2(a0.x, a0.y); pa.y = cvt2(a0.z, a0.w);
            pa.z = cvt2(a1.x, a1.y); pa.w = cvt2(a1.z, a1.w);
            *(uint4*)&As[s][woff] = pa;
            if (s < NIT - 1) { a0 = na0; a1 = na1; }
        }
    } else {
        const float* gB = Qf + (qrow0 + prow) * DIM + pchk * 8;
        float4 a0 = *(const float4*)(gA);
        float4 a1 = *(const float4*)(gA + 4);
        float4 b0 = *(const float4*)(gB);
        float4 b1 = *(const float4*)(gB + 4);
        #pragma unroll
        for (int s = 0; s < NIT; ++s) {
            float4 na0, na1, nb0, nb1;
            if (s < NIT - 1) {
                na0 = *(const float4*)(gA + (s + 1) * BK);
                na1 = *(const float4*)(gA + (s + 1) * BK + 4);
                nb0 = *(const float4*)(gB + (s + 1) * BK);
                nb1 = *(const float4*)(gB + (s + 1) * BK + 4);
            }
            sqp += sq8(a0, a1);
            sqq += sq8(b0, b1);
            uint4 pa, pb;
            pa.x = cvt2(a0.x, a0.y); pa.y = cvt2(a0.z, a0.w);
            pa.z = cvt2(a1.x, a1.y); pa.w = cvt2(a1.z, a1.w);
            pb.x = cvt2(b0.x, b0.y); pb.y = cvt2(b0.z, b0.w);
            pb.z = cvt2(b1.x, b1.y); pb.w = cvt2(b1.z, b1.w);
            *(uint4*)&As[s][woff] = pa;
            *(uint4*)&Bs[s][woff] = pb;
            if (s < NIT - 1) { a0 = na0; a1 = na1; b0 = nb0; b1 = nb1; }
        }
    }
    // per-row norm partials -> per-row totals (4 staging threads per row)
    sqp += __shfl_xor(sqp, 1); sqp += __shfl_xor(sqp, 2);
    sqq += __shfl_xor(sqq, 1); sqq += __shfl_xor(sqq, 2);

    __syncthreads();                        // barrier 1: panels visible

    // ================= K-loop: NO barriers, compiler-pipelined =============
    floatx4 acc[2][4];
    #pragma unroll
    for (int i = 0; i < 2; ++i)
        #pragma unroll
        for (int j = 0; j < 4; ++j) acc[i][j] = (floatx4)0.0f;

    const uint16_t* bbase = symdiag ? &As[0][0] : &Bs[0][0];
    #pragma unroll
    for (int it = 0; it < NIT; ++it) {
        const uint16_t* ab = &As[it][0];
        const uint16_t* bb = bbase + it * SLICE;
        short8 af[2], bfr[4];
        #pragma unroll
        for (int mi = 0; mi < 2; ++mi)
            af[mi] = *(const short8*)&ab[(rowbase + mi * 16 + l15) * BK + rsw];
        #pragma unroll
        for (int ni = 0; ni < 4; ++ni)
            bfr[ni] = *(const short8*)&bb[(colbase + ni * 16 + l15) * BK + rsw];
        #pragma unroll
        for (int mi = 0; mi < 2; ++mi)
            #pragma unroll
            for (int ni = 0; ni < 4; ++ni)
                acc[mi][ni] = __builtin_amdgcn_mfma_f32_16x16x32_bf16(
                    af[mi], bfr[ni], acc[mi][ni], 0, 0, 0);
    }

    // ================= norm share in dead LDS, then epilogue ===============
    __syncthreads();                        // barrier 2: all slice reads done
    if ((tid & 3) == 0) {
        nsh[prow] = sqp;
        nsh[TILE + prow] = symdiag ? sqp : sqq;
    }
    __syncthreads();                        // barrier 3: norms visible

    // C/D layout: col = lane&15, row = (lane>>4)*4 + reg.
    float lsum = 0.0f;
    #pragma unroll
    for (int mi = 0; mi < 2; ++mi) {
        #pragma unroll
        for (int i = 0; i < 4; ++i) {
            const int r = rowbase + mi * 16 + quad * 4 + i;
            const float rv = nsh[r];
            #pragma unroll
            for (int ni = 0; ni < 4; ++ni) {
                const int c = colbase + ni * 16 + l15;
                float d2 = rv + nsh[TILE + c] - 2.0f * acc[mi][ni][i];
                float s = sqrtf(fmaxf(d2, 0.0f));
                if (symdiag && (r == c)) s = 0.0f;
                lsum += s;
            }
        }
    }
    #pragma unroll
    for (int off = 32; off; off >>= 1) lsum += __shfl_down(lsum, off);
    if (lane == 0) nsh[2 * TILE + wv] = lsum;
    __syncthreads();                        // barrier 4: wave partials visible
    if (tid == 0) {
        float bs = 0.0f;
        #pragma unroll
        for (int i = 0; i < 8; ++i) bs += nsh[2 * TILE + i];
        atomicAdd(out, bs * (w * scale));
    }
}

// ---------------------------------------------------------------------------
extern "C" void kernel_launch(void* const* d_in, const int* in_sizes, int n_in,
                              void* d_out, int out_size, void* d_ws, size_t ws_size,
                              hipStream_t stream) {
    const float* X = (const float*)d_in[0];
    const float* Y = (const float*)d_in[1];
    const int total_elems = in_sizes[0];          // G*NPTS*DIM
    const int G = total_elems / (NPTS * DIM);     // 128

    float* out = (float*)d_out;
    hipMemsetAsync(out, 0, sizeof(float) * out_size, stream);

    const float scale = 1.0f / ((float)NPTS * (float)NPTS * (float)G);
    mmd_mono<<<10 * G, 512, 0, stream>>>(X, Y, out, scale, G);
}